// Round 1
// baseline (475.238 us; speedup 1.0000x reference)
//
#include <hip/hip_runtime.h>
#include <math.h>

constexpr int NB = 32;
constexpr int NS = 2048;
constexpr int NE = 1024;
constexpr int ND = 1024;

// -------------------------------------------------------------------------
// u[b,e] = sum_d Wa[d,e] * h[b,d]   (atomicAdd over d-chunks; u pre-zeroed)
// grid (NE/256, ND/128, NB/16), block 256
__global__ void k_u(const float* __restrict__ Wa, const float* __restrict__ h,
                    float* __restrict__ u) {
    __shared__ float hs[16][128];
    const int e  = blockIdx.x * 256 + threadIdx.x;
    const int d0 = blockIdx.y * 128;
    const int b0 = blockIdx.z * 16;
    for (int k = 0; k < 8; ++k) {
        int j  = k * 256 + threadIdx.x;
        int bb = j >> 7, dl = j & 127;
        hs[bb][dl] = h[(b0 + bb) * ND + d0 + dl];
    }
    __syncthreads();
    float acc[16];
#pragma unroll
    for (int bb = 0; bb < 16; ++bb) acc[bb] = 0.f;
    for (int dl = 0; dl < 128; ++dl) {
        float w = Wa[(size_t)(d0 + dl) * NE + e];   // coalesced over e
#pragma unroll
        for (int bb = 0; bb < 16; ++bb) acc[bb] = fmaf(w, hs[bb][dl], acc[bb]);
    }
#pragma unroll
    for (int bb = 0; bb < 16; ++bb)
        atomicAdd(&u[(b0 + bb) * NE + e], acc[bb]);
}

// -------------------------------------------------------------------------
// hp_pre[b,d] = sum_e Wp[d,e] * h[b,e]   (wave-per-d, 8 b's per block)
// grid (ND/32, NB/8), block 256
__global__ void k_hp(const float* __restrict__ Wp, const float* __restrict__ h,
                     float* __restrict__ hp_pre) {
    __shared__ float hs[8][1024];
    const int b0     = blockIdx.y * 8;
    const int d_base = blockIdx.x * 32;
    const float4* h4 = (const float4*)(h + (size_t)b0 * ND);
    float4* hs4 = (float4*)&hs[0][0];
    for (int k = 0; k < 8; ++k) hs4[k * 256 + threadIdx.x] = h4[k * 256 + threadIdx.x];
    __syncthreads();
    const int wave = threadIdx.x >> 6;
    const int lane = threadIdx.x & 63;
    for (int dd = 0; dd < 8; ++dd) {
        const int d = d_base + wave * 8 + dd;
        const float* wrow = Wp + (size_t)d * ND;
        float acc[8];
#pragma unroll
        for (int bb = 0; bb < 8; ++bb) acc[bb] = 0.f;
        for (int e = lane; e < ND; e += 64) {
            float w = wrow[e];   // coalesced
#pragma unroll
            for (int bb = 0; bb < 8; ++bb) acc[bb] = fmaf(w, hs[bb][e], acc[bb]);
        }
#pragma unroll
        for (int bb = 0; bb < 8; ++bb) {
            float v = acc[bb];
            for (int off = 32; off > 0; off >>= 1) v += __shfl_down(v, off);
            if (lane == 0) hp_pre[(b0 + bb) * ND + d] = v;
        }
    }
}

// -------------------------------------------------------------------------
// pos[b] = S * sigmoid(vp . tanh(hp_pre[b]+Wp_b) + vp_b);  cb[b] = Wa_b . h[b]
// fp64 accumulation (pos error is amplified by S*sigmoid' and the gauss slope)
// grid NB, block 256
__global__ void k_pos(const float* __restrict__ hp_pre, const float* __restrict__ Wp_b,
                      const float* __restrict__ vp_w, const float* __restrict__ vp_b,
                      const float* __restrict__ Wa_b, const float* __restrict__ h,
                      float* __restrict__ pos, float* __restrict__ cb) {
    const int b = blockIdx.x;
    double va = 0.0, ca = 0.0;
    for (int d = threadIdx.x; d < ND; d += 256) {
        double t = tanh((double)hp_pre[b * ND + d] + (double)Wp_b[d]);
        va += t * (double)vp_w[d];
        ca += (double)Wa_b[d] * (double)h[b * ND + d];
    }
    __shared__ double red[2][4];
    const int lane = threadIdx.x & 63, wave = threadIdx.x >> 6;
    for (int off = 32; off > 0; off >>= 1) {
        va += __shfl_down(va, off);
        ca += __shfl_down(ca, off);
    }
    if (lane == 0) { red[0][wave] = va; red[1][wave] = ca; }
    __syncthreads();
    if (threadIdx.x == 0) {
        double v = red[0][0] + red[0][1] + red[0][2] + red[0][3] + (double)vp_b[0];
        double c = red[1][0] + red[1][1] + red[1][2] + red[1][3];
        pos[b] = (float)((double)NS / (1.0 + exp(-v)));
        cb[b]  = (float)c;
    }
}

// -------------------------------------------------------------------------
// att[b,s] = enc[b,s,:] . u[b] + cb[b]   (wave-per-s; the 256 MB pass)
// grid (NS/4, NB), block 256
__global__ void __launch_bounds__(256) k_att(const float* __restrict__ enc,
                                             const float* __restrict__ u,
                                             const float* __restrict__ cb,
                                             float* __restrict__ att) {
    __shared__ float4 us[256];
    const int b    = blockIdx.y;
    const int wave = threadIdx.x >> 6, lane = threadIdx.x & 63;
    const int s    = blockIdx.x * 4 + wave;
    us[threadIdx.x] = ((const float4*)(u + (size_t)b * NE))[threadIdx.x];
    __syncthreads();
    const float4* erow = (const float4*)(enc + ((size_t)b * NS + s) * NE);
    float acc = 0.f;
#pragma unroll
    for (int i = 0; i < 4; ++i) {
        float4 ev = erow[i * 64 + lane];
        float4 uv = us[i * 64 + lane];
        acc += ev.x * uv.x + ev.y * uv.y + ev.z * uv.z + ev.w * uv.w;
    }
    for (int off = 32; off > 0; off >>= 1) acc += __shfl_down(acc, off);
    if (lane == 0) att[b * NS + s] = acc + cb[b];
}

// -------------------------------------------------------------------------
// alpha[b,s] = exp(att - m)/Z * exp(-(s-pos)^2/8), in place over att buffer
// grid NB, block 256 (each block owns row b: reads att into regs before write)
__global__ void k_alpha(float* __restrict__ alpha, const float* __restrict__ pos) {
    const int b = blockIdx.x;
    __shared__ float red[4];
    __shared__ float m_sh, z_sh;
    float av[8];
    float lm = -3.4e38f;
#pragma unroll
    for (int k = 0; k < 8; ++k) {
        av[k] = alpha[b * NS + k * 256 + threadIdx.x];
        lm = fmaxf(lm, av[k]);
    }
    const int lane = threadIdx.x & 63, wave = threadIdx.x >> 6;
    for (int off = 32; off > 0; off >>= 1) lm = fmaxf(lm, __shfl_down(lm, off));
    if (lane == 0) red[wave] = lm;
    __syncthreads();
    if (threadIdx.x == 0) m_sh = fmaxf(fmaxf(red[0], red[1]), fmaxf(red[2], red[3]));
    __syncthreads();
    const float m = m_sh;
    float ls = 0.f;
#pragma unroll
    for (int k = 0; k < 8; ++k) ls += expf(av[k] - m);
    for (int off = 32; off > 0; off >>= 1) ls += __shfl_down(ls, off);
    if (lane == 0) red[wave] = ls;
    __syncthreads();
    if (threadIdx.x == 0) z_sh = red[0] + red[1] + red[2] + red[3];
    __syncthreads();
    const float invZ = 1.f / z_sh;
    const float p = pos[b];
#pragma unroll
    for (int k = 0; k < 8; ++k) {
        const int s = k * 256 + threadIdx.x;
        const float dp = (float)s - p;
        alpha[b * NS + s] = expf((av[k] - m) - dp * dp * 0.125f) * invZ;
    }
}

// -------------------------------------------------------------------------
// awe[b,e] = sum_s alpha[b,s] * enc[b,s,e], restricted to the 128-row window
// around pos[b] (alpha is exactly 0 in fp32 beyond |s-pos| ~ 29).
// grid (16, NB) — 16 chunks x 8 rows; block 256; atomicAdd (awe pre-zeroed)
__global__ void k_awe(const float* __restrict__ enc, const float* __restrict__ pos,
                      const float* __restrict__ alpha, float* __restrict__ awe) {
    const int b = blockIdx.y;
    int s0 = (int)floorf(pos[b]) - 63;
    if (s0 < 0) s0 = 0;
    if (s0 > NS - 128) s0 = NS - 128;
    const int sbase = s0 + blockIdx.x * 8;
    __shared__ float as[8];
    if (threadIdx.x < 8) as[threadIdx.x] = alpha[b * NS + sbase + threadIdx.x];
    __syncthreads();
    float4 acc = {0.f, 0.f, 0.f, 0.f};
    const float4* ebase = (const float4*)(enc + ((size_t)b * NS + sbase) * NE);
    for (int r = 0; r < 8; ++r) {
        const float a = as[r];
        if (a == 0.f) continue;          // uniform branch: skip zero-weight rows
        float4 ev = ebase[(size_t)r * 256 + threadIdx.x];
        acc.x = fmaf(a, ev.x, acc.x);
        acc.y = fmaf(a, ev.y, acc.y);
        acc.z = fmaf(a, ev.z, acc.z);
        acc.w = fmaf(a, ev.w, acc.w);
    }
    float* dst = awe + (size_t)b * NE + threadIdx.x * 4;
    atomicAdd(dst + 0, acc.x);
    atomicAdd(dst + 1, acc.y);
    atomicAdd(dst + 2, acc.z);
    atomicAdd(dst + 3, acc.w);
}

// -------------------------------------------------------------------------
extern "C" void kernel_launch(void* const* d_in, const int* in_sizes, int n_in,
                              void* d_out, int out_size, void* d_ws, size_t ws_size,
                              hipStream_t stream) {
    const float* enc  = (const float*)d_in[0];
    const float* h    = (const float*)d_in[1];
    // d_in[2] currentPosition: unused by the reference
    const float* Wa_w = (const float*)d_in[3];
    const float* Wa_b = (const float*)d_in[4];
    const float* Wp_w = (const float*)d_in[5];
    const float* Wp_b = (const float*)d_in[6];
    const float* vp_w = (const float*)d_in[7];
    const float* vp_b = (const float*)d_in[8];

    float* out   = (float*)d_out;
    float* awe   = out;            // [NB*NE]
    float* alpha = out + NB * NE;  // [NB*NS]  (also used as the att buffer)

    float* ws     = (float*)d_ws;
    float* u      = ws;                      // NB*NE
    float* hp_pre = ws + NB * NE;            // NB*ND
    float* pos    = ws + NB * NE + NB * ND;  // NB
    float* cbuf   = pos + NB;                // NB

    hipMemsetAsync(u, 0, (size_t)NB * NE * sizeof(float), stream);
    hipMemsetAsync(awe, 0, (size_t)NB * NE * sizeof(float), stream);

    k_u  <<<dim3(NE / 256, ND / 128, NB / 16), 256, 0, stream>>>(Wa_w, h, u);
    k_hp <<<dim3(ND / 32, NB / 8),             256, 0, stream>>>(Wp_w, h, hp_pre);
    k_pos<<<NB,                                256, 0, stream>>>(hp_pre, Wp_b, vp_w, vp_b, Wa_b, h, pos, cbuf);
    k_att<<<dim3(NS / 4, NB),                  256, 0, stream>>>(enc, u, cbuf, alpha);
    k_alpha<<<NB,                              256, 0, stream>>>(alpha, pos);
    k_awe<<<dim3(16, NB),                      256, 0, stream>>>(enc, pos, alpha, awe);
}

// Round 2
// 473.237 us; speedup vs baseline: 1.0042x; 1.0042x over previous
//
#include <hip/hip_runtime.h>
#include <math.h>

constexpr int NB = 32;
constexpr int NS = 2048;
constexpr int NE = 1024;
constexpr int ND = 1024;

// -------------------------------------------------------------------------
// u[b,e] = sum_d Wa[d,e] * h[b,d]   — full-depth per block, direct store.
// grid (NE/64, NB), block 256: el = tid&63 (e), strip = tid>>6 (4 strips x 256 d)
__global__ void k_u(const float* __restrict__ Wa, const float* __restrict__ h,
                    float* __restrict__ u) {
    __shared__ float hs[1024];
    __shared__ float part[4][64];
    const int b  = blockIdx.y;
    const int e0 = blockIdx.x * 64;
    ((float4*)hs)[threadIdx.x] = ((const float4*)(h + (size_t)b * ND))[threadIdx.x];
    __syncthreads();
    const int el    = threadIdx.x & 63;
    const int strip = threadIdx.x >> 6;
    const int e     = e0 + el;
    const int d0    = strip * 256;
    float acc = 0.f;
#pragma unroll 8
    for (int dd = 0; dd < 256; ++dd)
        acc = fmaf(Wa[(size_t)(d0 + dd) * NE + e], hs[d0 + dd], acc);
    part[strip][el] = acc;
    __syncthreads();
    if (threadIdx.x < 64)
        u[(size_t)b * NE + e0 + threadIdx.x] =
            part[0][threadIdx.x] + part[1][threadIdx.x] +
            part[2][threadIdx.x] + part[3][threadIdx.x];
}

// -------------------------------------------------------------------------
// hp_pre[b,d] = sum_e Wp[d,e] * h[b,e]   (wave-per-d-octet, 8 b's per block)
// grid (ND/32, NB/8), block 256
__global__ void k_hp(const float* __restrict__ Wp, const float* __restrict__ h,
                     float* __restrict__ hp_pre) {
    __shared__ float hs[8][1024];
    const int b0     = blockIdx.y * 8;
    const int d_base = blockIdx.x * 32;
    const float4* h4 = (const float4*)(h + (size_t)b0 * ND);
    float4* hs4 = (float4*)&hs[0][0];
    for (int k = 0; k < 8; ++k) hs4[k * 256 + threadIdx.x] = h4[k * 256 + threadIdx.x];
    __syncthreads();
    const int wave = threadIdx.x >> 6;
    const int lane = threadIdx.x & 63;
    for (int dd = 0; dd < 8; ++dd) {
        const int d = d_base + wave * 8 + dd;
        const float* wrow = Wp + (size_t)d * ND;
        float acc[8];
#pragma unroll
        for (int bb = 0; bb < 8; ++bb) acc[bb] = 0.f;
        for (int e = lane; e < ND; e += 64) {
            float w = wrow[e];
#pragma unroll
            for (int bb = 0; bb < 8; ++bb) acc[bb] = fmaf(w, hs[bb][e], acc[bb]);
        }
#pragma unroll
        for (int bb = 0; bb < 8; ++bb) {
            float v = acc[bb];
            for (int off = 32; off > 0; off >>= 1) v += __shfl_down(v, off);
            if (lane == 0) hp_pre[(b0 + bb) * ND + d] = v;
        }
    }
}

// -------------------------------------------------------------------------
// pos[b] = S * sigmoid(vp . tanh(hp_pre[b]+Wp_b) + vp_b);  cb[b] = Wa_b . h[b]
// fp64 chain: pos error is amplified by S*sigmoid' (x512) and the gauss slope.
// grid NB, block 256
__global__ void k_pos(const float* __restrict__ hp_pre, const float* __restrict__ Wp_b,
                      const float* __restrict__ vp_w, const float* __restrict__ vp_b,
                      const float* __restrict__ Wa_b, const float* __restrict__ h,
                      float* __restrict__ pos, float* __restrict__ cb) {
    const int b = blockIdx.x;
    double va = 0.0, ca = 0.0;
    for (int d = threadIdx.x; d < ND; d += 256) {
        double t = tanh((double)hp_pre[b * ND + d] + (double)Wp_b[d]);
        va += t * (double)vp_w[d];
        ca += (double)Wa_b[d] * (double)h[b * ND + d];
    }
    __shared__ double red[2][4];
    const int lane = threadIdx.x & 63, wave = threadIdx.x >> 6;
    for (int off = 32; off > 0; off >>= 1) {
        va += __shfl_down(va, off);
        ca += __shfl_down(ca, off);
    }
    if (lane == 0) { red[0][wave] = va; red[1][wave] = ca; }
    __syncthreads();
    if (threadIdx.x == 0) {
        double v = red[0][0] + red[0][1] + red[0][2] + red[0][3] + (double)vp_b[0];
        double c = red[1][0] + red[1][1] + red[1][2] + red[1][3];
        pos[b] = (float)((double)NS / (1.0 + exp(-v)));
        cb[b]  = (float)c;
    }
}

// -------------------------------------------------------------------------
// att[b,s] = enc[b,s,:] . u[b] + cb[b]   — the 256 MB pass. 32 rows/block
// (8 rows/wave) so u's LDS fill amortizes 8x better than 4 rows/block.
// grid (NS/32, NB), block 256
__global__ void __launch_bounds__(256) k_att(const float* __restrict__ enc,
                                             const float* __restrict__ u,
                                             const float* __restrict__ cb,
                                             float* __restrict__ att) {
    __shared__ float4 us[256];
    const int b    = blockIdx.y;
    const int wave = threadIdx.x >> 6, lane = threadIdx.x & 63;
    us[threadIdx.x] = ((const float4*)(u + (size_t)b * NE))[threadIdx.x];
    __syncthreads();
    const float cbv   = cb[b];
    const int  s_base = blockIdx.x * 32 + wave * 8;
#pragma unroll 2
    for (int r = 0; r < 8; ++r) {
        const int s = s_base + r;
        const float4* erow = (const float4*)(enc + ((size_t)b * NS + s) * NE);
        float acc = 0.f;
#pragma unroll
        for (int i = 0; i < 4; ++i) {
            float4 ev = erow[i * 64 + lane];
            float4 uv = us[i * 64 + lane];
            acc += ev.x * uv.x + ev.y * uv.y + ev.z * uv.z + ev.w * uv.w;
        }
        for (int off = 32; off > 0; off >>= 1) acc += __shfl_down(acc, off);
        if (lane == 0) att[b * NS + s] = acc + cbv;
    }
}

// -------------------------------------------------------------------------
// Fused: alpha[b,s] = softmax(att)[s] * exp(-(s-pos)^2/8) (in place), then
// awe[b,:] = sum over the 128-row window around pos (alpha is exactly 0 in
// fp32 beyond |s-pos| ~ 29, so the window sum equals the full sum).
// grid NB, block 256. Direct store to awe — no memset, no atomics.
__global__ void k_alpha_awe(float* __restrict__ alpha, const float* __restrict__ pos,
                            const float* __restrict__ enc, float* __restrict__ awe) {
    const int b = blockIdx.x;
    __shared__ float red[4];
    __shared__ float m_sh, z_sh;
    __shared__ float asw[128];
    float av[8];
    float lm = -3.4e38f;
#pragma unroll
    for (int k = 0; k < 8; ++k) {
        av[k] = alpha[b * NS + k * 256 + threadIdx.x];
        lm = fmaxf(lm, av[k]);
    }
    const int lane = threadIdx.x & 63, wave = threadIdx.x >> 6;
    for (int off = 32; off > 0; off >>= 1) lm = fmaxf(lm, __shfl_down(lm, off));
    if (lane == 0) red[wave] = lm;
    __syncthreads();
    if (threadIdx.x == 0) m_sh = fmaxf(fmaxf(red[0], red[1]), fmaxf(red[2], red[3]));
    __syncthreads();
    const float m = m_sh;
    float ls = 0.f;
#pragma unroll
    for (int k = 0; k < 8; ++k) ls += expf(av[k] - m);
    for (int off = 32; off > 0; off >>= 1) ls += __shfl_down(ls, off);
    if (lane == 0) red[wave] = ls;
    __syncthreads();
    if (threadIdx.x == 0) z_sh = red[0] + red[1] + red[2] + red[3];
    __syncthreads();
    const float invZ = 1.f / z_sh;
    const float p = pos[b];
    int s0 = (int)floorf(p) - 63;
    if (s0 < 0) s0 = 0;
    if (s0 > NS - 128) s0 = NS - 128;
#pragma unroll
    for (int k = 0; k < 8; ++k) {
        const int s = k * 256 + threadIdx.x;
        const float dp = (float)s - p;
        const float a = expf((av[k] - m) - dp * dp * 0.125f) * invZ;
        alpha[b * NS + s] = a;
        const int w = s - s0;
        if ((unsigned)w < 128u) asw[w] = a;
    }
    __syncthreads();
    float4 acc = {0.f, 0.f, 0.f, 0.f};
    const float4* ebase = (const float4*)(enc + ((size_t)b * NS + s0) * NE);
#pragma unroll 8
    for (int r = 0; r < 128; ++r) {
        const float a = asw[r];
        float4 ev = ebase[(size_t)r * 256 + threadIdx.x];
        acc.x = fmaf(a, ev.x, acc.x);
        acc.y = fmaf(a, ev.y, acc.y);
        acc.z = fmaf(a, ev.z, acc.z);
        acc.w = fmaf(a, ev.w, acc.w);
    }
    ((float4*)(awe + (size_t)b * NE))[threadIdx.x] = acc;
}

// -------------------------------------------------------------------------
extern "C" void kernel_launch(void* const* d_in, const int* in_sizes, int n_in,
                              void* d_out, int out_size, void* d_ws, size_t ws_size,
                              hipStream_t stream) {
    const float* enc  = (const float*)d_in[0];
    const float* h    = (const float*)d_in[1];
    // d_in[2] currentPosition: unused by the reference
    const float* Wa_w = (const float*)d_in[3];
    // d_in[4] Wa_b used in k_pos (cb term)
    const float* Wa_b = (const float*)d_in[4];
    const float* Wp_w = (const float*)d_in[5];
    const float* Wp_b = (const float*)d_in[6];
    const float* vp_w = (const float*)d_in[7];
    const float* vp_b = (const float*)d_in[8];

    float* out   = (float*)d_out;
    float* awe   = out;            // [NB*NE]
    float* alpha = out + NB * NE;  // [NB*NS]  (also the att scratch)

    float* ws     = (float*)d_ws;
    float* u      = ws;                      // NB*NE
    float* hp_pre = ws + NB * NE;            // NB*ND
    float* pos    = ws + NB * NE + NB * ND;  // NB
    float* cbuf   = pos + NB;                // NB

    k_u  <<<dim3(NE / 64, NB), 256, 0, stream>>>(Wa_w, h, u);
    k_hp <<<dim3(ND / 32, NB / 8), 256, 0, stream>>>(Wp_w, h, hp_pre);
    k_pos<<<NB, 256, 0, stream>>>(hp_pre, Wp_b, vp_w, vp_b, Wa_b, h, pos, cbuf);
    k_att<<<dim3(NS / 32, NB), 256, 0, stream>>>(enc, u, cbuf, alpha);
    k_alpha_awe<<<NB, 256, 0, stream>>>(alpha, pos, enc, awe);
}

// Round 3
// 453.559 us; speedup vs baseline: 1.0478x; 1.0434x over previous
//
#include <hip/hip_runtime.h>
#include <math.h>

constexpr int NB = 32;
constexpr int NS = 2048;
constexpr int NE = 1024;
constexpr int ND = 1024;

// -------------------------------------------------------------------------
// Merged small-GEMV kernel, one dispatch:
//   blocks [0,512):  u[b,e] = sum_d Wa[d,e]*h[b,d]   (block = 64 e's x 1 b)
//   blocks [512,640): hp_pre[b,d] = sum_e Wp[d,e]*h[b,e] (block = 32 d's x 8 b)
__global__ void __launch_bounds__(256) k_small(const float* __restrict__ Wa,
                                               const float* __restrict__ Wp,
                                               const float* __restrict__ h,
                                               float* __restrict__ u,
                                               float* __restrict__ hp_pre) {
    __shared__ float smem[8 * 1024];
    const int bid = blockIdx.x;
    if (bid < 512) {
        float* hs   = smem;          // [1024]
        float* part = smem + 1024;   // [4][64]
        const int b  = bid >> 4;
        const int e0 = (bid & 15) * 64;
        ((float4*)hs)[threadIdx.x] = ((const float4*)(h + (size_t)b * ND))[threadIdx.x];
        __syncthreads();
        const int el    = threadIdx.x & 63;
        const int strip = threadIdx.x >> 6;
        const int e     = e0 + el;
        const int d0    = strip * 256;
        float acc = 0.f;
#pragma unroll 8
        for (int dd = 0; dd < 256; ++dd)
            acc = fmaf(Wa[(size_t)(d0 + dd) * NE + e], hs[d0 + dd], acc);
        part[strip * 64 + el] = acc;
        __syncthreads();
        if (threadIdx.x < 64)
            u[(size_t)b * NE + e0 + threadIdx.x] =
                part[threadIdx.x] + part[64 + threadIdx.x] +
                part[128 + threadIdx.x] + part[192 + threadIdx.x];
    } else {
        float (*hs)[1024] = (float(*)[1024])smem;   // [8][1024]
        const int j      = bid - 512;
        const int b0     = (j >> 5) * 8;
        const int d_base = (j & 31) * 32;
        const float4* h4 = (const float4*)(h + (size_t)b0 * ND);
        float4* hs4 = (float4*)&hs[0][0];
        for (int k = 0; k < 8; ++k) hs4[k * 256 + threadIdx.x] = h4[k * 256 + threadIdx.x];
        __syncthreads();
        const int wave = threadIdx.x >> 6;
        const int lane = threadIdx.x & 63;
        for (int dd = 0; dd < 8; ++dd) {
            const int d = d_base + wave * 8 + dd;
            const float* wrow = Wp + (size_t)d * ND;
            float acc[8];
#pragma unroll
            for (int bb = 0; bb < 8; ++bb) acc[bb] = 0.f;
            for (int e = lane; e < ND; e += 64) {
                float w = wrow[e];
#pragma unroll
                for (int bb = 0; bb < 8; ++bb) acc[bb] = fmaf(w, hs[bb][e], acc[bb]);
            }
#pragma unroll
            for (int bb = 0; bb < 8; ++bb) {
                float v = acc[bb];
                for (int off = 32; off > 0; off >>= 1) v += __shfl_down(v, off);
                if (lane == 0) hp_pre[(b0 + bb) * ND + d] = v;
            }
        }
    }
}

// -------------------------------------------------------------------------
// pos[b] = S * sigmoid(vp . tanh(hp_pre[b]+Wp_b) + vp_b);  cb[b] = Wa_b . h[b]
// fp64 chain: pos error is amplified by S*sigmoid' and the gauss slope.
__global__ void k_pos(const float* __restrict__ hp_pre, const float* __restrict__ Wp_b,
                      const float* __restrict__ vp_w, const float* __restrict__ vp_b,
                      const float* __restrict__ Wa_b, const float* __restrict__ h,
                      float* __restrict__ pos, float* __restrict__ cb) {
    const int b = blockIdx.x;
    double va = 0.0, ca = 0.0;
    for (int d = threadIdx.x; d < ND; d += 256) {
        double t = tanh((double)hp_pre[b * ND + d] + (double)Wp_b[d]);
        va += t * (double)vp_w[d];
        ca += (double)Wa_b[d] * (double)h[b * ND + d];
    }
    __shared__ double red[2][4];
    const int lane = threadIdx.x & 63, wave = threadIdx.x >> 6;
    for (int off = 32; off > 0; off >>= 1) {
        va += __shfl_down(va, off);
        ca += __shfl_down(ca, off);
    }
    if (lane == 0) { red[0][wave] = va; red[1][wave] = ca; }
    __syncthreads();
    if (threadIdx.x == 0) {
        double v = red[0][0] + red[0][1] + red[0][2] + red[0][3] + (double)vp_b[0];
        double c = red[1][0] + red[1][1] + red[1][2] + red[1][3];
        pos[b] = (float)((double)NS / (1.0 + exp(-v)));
        cb[b]  = (float)c;
    }
}

// -------------------------------------------------------------------------
// att[b,s] = enc[b,s,:] . u[b] + cb[b]  — the 256 MB pass (BW-bound floor).
// grid (NS/32, NB), block 256; 8 rows per wave.
__global__ void __launch_bounds__(256) k_att(const float* __restrict__ enc,
                                             const float* __restrict__ u,
                                             const float* __restrict__ cb,
                                             float* __restrict__ att) {
    __shared__ float4 us[256];
    const int b    = blockIdx.y;
    const int wave = threadIdx.x >> 6, lane = threadIdx.x & 63;
    us[threadIdx.x] = ((const float4*)(u + (size_t)b * NE))[threadIdx.x];
    __syncthreads();
    const float cbv   = cb[b];
    const int  s_base = blockIdx.x * 32 + wave * 8;
#pragma unroll 2
    for (int r = 0; r < 8; ++r) {
        const int s = s_base + r;
        const float4* erow = (const float4*)(enc + ((size_t)b * NS + s) * NE);
        float acc = 0.f;
#pragma unroll
        for (int i = 0; i < 4; ++i) {
            float4 ev = erow[i * 64 + lane];
            float4 uv = us[i * 64 + lane];
            acc += ev.x * uv.x + ev.y * uv.y + ev.z * uv.z + ev.w * uv.w;
        }
        for (int off = 32; off > 0; off >>= 1) acc += __shfl_down(acc, off);
        if (lane == 0) att[b * NS + s] = acc + cbv;
    }
}

// -------------------------------------------------------------------------
// Per-b softmax stats (m, Z) over att; also zeros awe[b,:] for k_finish's
// atomics. grid NB, block 256.
__global__ void k_stats(const float* __restrict__ att, float* __restrict__ mz,
                        float* __restrict__ awe) {
    const int b = blockIdx.x;
    ((float4*)(awe + (size_t)b * NE))[threadIdx.x] = float4{0.f, 0.f, 0.f, 0.f};
    __shared__ float red[4];
    float av[8];
    float lm = -3.4e38f;
#pragma unroll
    for (int k = 0; k < 8; ++k) {
        av[k] = att[b * NS + k * 256 + threadIdx.x];
        lm = fmaxf(lm, av[k]);
    }
    const int lane = threadIdx.x & 63, wave = threadIdx.x >> 6;
    for (int off = 32; off > 0; off >>= 1) lm = fmaxf(lm, __shfl_down(lm, off));
    if (lane == 0) red[wave] = lm;
    __syncthreads();
    __shared__ float m_sh;
    if (threadIdx.x == 0) m_sh = fmaxf(fmaxf(red[0], red[1]), fmaxf(red[2], red[3]));
    __syncthreads();
    const float m = m_sh;
    float ls = 0.f;
#pragma unroll
    for (int k = 0; k < 8; ++k) ls += expf(av[k] - m);
    for (int off = 32; off > 0; off >>= 1) ls += __shfl_down(ls, off);
    if (lane == 0) red[wave] = ls;
    __syncthreads();
    if (threadIdx.x == 0) {
        mz[2 * b]     = m;
        mz[2 * b + 1] = red[0] + red[1] + red[2] + red[3];
    }
}

// -------------------------------------------------------------------------
// alpha[b,s] = exp(att-m-(s-pos)^2/8)/Z  written for the block's 512-s chunk;
// awe partial over 32 of the 128 window rows (alpha==0 in fp32 outside
// |s-pos|~29), atomicAdd into pre-zeroed awe. grid (4, NB), block 256.
__global__ void __launch_bounds__(256) k_finish(const float* __restrict__ att,
                                                const float* __restrict__ mz,
                                                const float* __restrict__ pos,
                                                const float* __restrict__ enc,
                                                float* __restrict__ alpha,
                                                float* __restrict__ awe) {
    const int b = blockIdx.y, c = blockIdx.x;
    const float m    = mz[2 * b];
    const float invZ = 1.f / mz[2 * b + 1];
    const float p    = pos[b];
    int s0 = (int)floorf(p) - 63;
    if (s0 < 0) s0 = 0;
    if (s0 > NS - 128) s0 = NS - 128;
    __shared__ float asw[32];
#pragma unroll
    for (int k = 0; k < 2; ++k) {
        const int s = c * 512 + k * 256 + threadIdx.x;
        const float dp = (float)s - p;
        alpha[b * NS + s] = expf(att[b * NS + s] - m - dp * dp * 0.125f) * invZ;
    }
    if (threadIdx.x < 32) {
        const int sr = s0 + c * 32 + threadIdx.x;
        const float dp = (float)sr - p;
        asw[threadIdx.x] = expf(att[b * NS + sr] - m - dp * dp * 0.125f) * invZ;
    }
    __syncthreads();
    float4 acc = {0.f, 0.f, 0.f, 0.f};
    const float4* ebase = (const float4*)(enc + ((size_t)b * NS + s0 + c * 32) * NE);
#pragma unroll 4
    for (int r = 0; r < 32; ++r) {
        const float a = asw[r];
        float4 ev = ebase[(size_t)r * 256 + threadIdx.x];
        acc.x = fmaf(a, ev.x, acc.x);
        acc.y = fmaf(a, ev.y, acc.y);
        acc.z = fmaf(a, ev.z, acc.z);
        acc.w = fmaf(a, ev.w, acc.w);
    }
    float* dst = awe + (size_t)b * NE + threadIdx.x * 4;
    atomicAdd(dst + 0, acc.x);
    atomicAdd(dst + 1, acc.y);
    atomicAdd(dst + 2, acc.z);
    atomicAdd(dst + 3, acc.w);
}

// -------------------------------------------------------------------------
extern "C" void kernel_launch(void* const* d_in, const int* in_sizes, int n_in,
                              void* d_out, int out_size, void* d_ws, size_t ws_size,
                              hipStream_t stream) {
    const float* enc  = (const float*)d_in[0];
    const float* h    = (const float*)d_in[1];
    // d_in[2] currentPosition: unused by the reference
    const float* Wa_w = (const float*)d_in[3];
    const float* Wa_b = (const float*)d_in[4];
    const float* Wp_w = (const float*)d_in[5];
    const float* Wp_b = (const float*)d_in[6];
    const float* vp_w = (const float*)d_in[7];
    const float* vp_b = (const float*)d_in[8];

    float* out   = (float*)d_out;
    float* awe   = out;            // [NB*NE]
    float* alpha = out + NB * NE;  // [NB*NS]

    float* ws     = (float*)d_ws;
    float* u      = ws;                       // NB*NE
    float* hp_pre = u + NB * NE;              // NB*ND
    float* pos    = hp_pre + NB * ND;         // NB
    float* cbuf   = pos + NB;                 // NB
    float* att    = cbuf + NB;                // NB*NS
    float* mz     = att + NB * NS;            // 2*NB

    k_small <<<640, 256, 0, stream>>>(Wa_w, Wp_w, h, u, hp_pre);
    k_pos   <<<NB, 256, 0, stream>>>(hp_pre, Wp_b, vp_w, vp_b, Wa_b, h, pos, cbuf);
    k_att   <<<dim3(NS / 32, NB), 256, 0, stream>>>(enc, u, cbuf, att);
    k_stats <<<NB, 256, 0, stream>>>(att, mz, awe);
    k_finish<<<dim3(4, NB), 256, 0, stream>>>(att, mz, pos, enc, alpha, awe);
}